// Round 7
// baseline (1056.400 us; speedup 1.0000x reference)
//
#include <hip/hip_runtime.h>
#include <math.h>

#define NSTEPS 500
#define BATCH  1024
#define DX     32
#define DW     32
#define HDIM   128
#define BETA   0.5f
#define EPSG   1e-4f
#define SC     2.8853900817779268f   // 2*log2(e): pre-scale for exp2-based sigmoid

typedef short bf8_t __attribute__((ext_vector_type(8)));
typedef float f4_t  __attribute__((ext_vector_type(4)));

union U8 { bf8_t v; unsigned u[4]; };

__device__ __forceinline__ f4_t MFMA(bf8_t a, bf8_t b, f4_t c) {
    return __builtin_amdgcn_mfma_f32_16x16x32_bf16(a, b, c, 0, 0, 0);
}

__device__ __forceinline__ unsigned short f2bf(float x) {   // RNE f32->bf16
    unsigned u = __float_as_uint(x);
    u += 0x7fffu + ((u >> 16) & 1u);
    return (unsigned short)(u >> 16);
}
__device__ __forceinline__ float bf2f(unsigned short h) {
    return __uint_as_float(((unsigned)h) << 16);
}
__device__ __forceinline__ unsigned cvtpk(float a, float b) {
    unsigned r;
    asm("v_cvt_pk_bf16_f32 %0, %1, %2" : "=v"(r) : "v"(a), "v"(b));
    return r;
}
__device__ __forceinline__ float unplo(unsigned u) { return __uint_as_float(u << 16); }
__device__ __forceinline__ float unphi(unsigned u) { return __uint_as_float(u & 0xffff0000u); }

__device__ __forceinline__ float exp2_hw(float x) {
    float r; asm("v_exp_f32 %0, %1" : "=v"(r) : "v"(x)); return r;
}
__device__ __forceinline__ float rcp_hw(float x) {
    float r; asm("v_rcp_f32 %0, %1" : "=v"(r) : "v"(x)); return r;
}
// sg = 1/(2^zs + 1); tanh(z) = 1 - 2*sg folded into next layer's weights/bias
__device__ __forceinline__ float sigm_s(float zs) {
    return rcp_hw(exp2_hw(zs) + 1.f);
}
__device__ __forceinline__ void hilo_pk(float a, float b, unsigned& hp, unsigned& lp) {
    hp = cvtpk(a, b);
    lp = cvtpk(a - unplo(hp), b - unphi(hp));
}
__device__ __forceinline__ void agpr_pin(bf8_t& v) { asm("" : "+a"(v)); }

// LDS barrier: orders LDS (lgkmcnt) but lets global loads/stores float across.
__device__ __forceinline__ void bar_lds() {
    __builtin_amdgcn_sched_barrier(0);
    asm volatile("s_waitcnt lgkmcnt(0)" ::: "memory");
    __builtin_amdgcn_s_barrier();
    __builtin_amdgcn_s_barrier();
    __builtin_amdgcn_sched_barrier(0);
}

// ============================================================================
// Round 7: TWO independent 16-row batch tiles (A,B) per block, interleaved in
// the same 4-wave 3-barrier structure as round 6.  Tile A's LDS/MFMA/trans
// latencies hide under tile B's issue (and vice versa); barriers amortize
// over 2 tiles.  Weights (AGPR), cin (t-only), bmu/vtr shared; only x/dW
// state and activations duplicate.  grid = BATCH/32 = 32 blocks.
// ============================================================================
__global__ __launch_bounds__(256, 1)
void sde_kernel(const float* __restrict__ x0, const float* __restrict__ ts,
                const float* __restrict__ dWs,
                const float* __restrict__ W1, const float* __restrict__ b1,
                const float* __restrict__ W2, const float* __restrict__ b2,
                const float* __restrict__ W3, const float* __restrict__ b3,
                const float* __restrict__ G,  const float* __restrict__ mu,
                const float* __restrict__ vt, float* __restrict__ out)
{
    __shared__ float sts[NSTEPS + 1];
    __shared__ __align__(16) float sG[DX * DW];
    __shared__ __align__(16) unsigned sH1[2][4][64][4];
    __shared__ __align__(16) unsigned sB2[2][4][64][4];
    __shared__ __align__(16) unsigned sUH[2][2][64][2];
    __shared__ __align__(16) unsigned sUL[2][2][64][2];
    __shared__ __align__(16) f4_t sRA[2][2][64];
    __shared__ float sLL[2][2][16];

    const int tid  = threadIdx.x;
    const int w    = tid >> 6;       // wave id 0..3
    const int lane = tid & 63;
    const int m16  = lane & 15;      // batch column
    const int quad = lane >> 4;
    const int r0   = blockIdx.x * 32;
    const int browA = r0 + m16;
    const int browB = r0 + 16 + m16;

    for (int i = tid; i <= NSTEPS; i += 256) sts[i] = ts[i];
    for (int i = tid; i < DX * DW; i += 256) sG[i] = G[i];
    __syncthreads();

    // sigma k-slot map (group-local, 32-wide) and k-tile rotation
    int foS[8], ktG[4];
    #pragma unroll
    for (int j = 0; j < 8; ++j) foS[j] = (j < 4) ? (4 * quad + j) : (16 + 4 * quad + (j - 4));
    #pragma unroll
    for (int kf = 0; kf < 4; ++kf) ktG[kf] = (w + kf) & 3;

    // ---- L1/L2 weight fragments (own 2 m-tiles, features (2w+ml)*16+m16) ----
    bf8_t w1a[2];
    #pragma unroll
    for (int ml = 0; ml < 2; ++ml) {
        int mtg = 2 * w + ml;
        #pragma unroll
        for (int j = 0; j < 8; ++j)
            w1a[ml][j] = (short)f2bf(SC * W1[(1 + foS[j]) * HDIM + mtg * 16 + m16]);
        agpr_pin(w1a[ml]);
    }
    bf8_t w2a[2][4];
    #pragma unroll
    for (int ml = 0; ml < 2; ++ml) {
        int mtg = 2 * w + ml;
        #pragma unroll
        for (int kf = 0; kf < 4; ++kf) {
            #pragma unroll
            for (int j = 0; j < 8; ++j)
                w2a[ml][kf][j] = (short)f2bf(-2.f * SC * W2[(ktG[kf] * 32 + foS[j]) * HDIM + mtg * 16 + m16]);
            agpr_pin(w2a[ml][kf]);
        }
    }

    bf8_t ones;
    #pragma unroll
    for (int j = 0; j < 8; ++j) ones[j] = (short)0x3f80;

    // folded C-inits
    f4_t b2C[2];
    #pragma unroll
    for (int ml = 0; ml < 2; ++ml) {
        f4_t S = {0, 0, 0, 0};
        #pragma unroll
        for (int kf = 0; kf < 4; ++kf) S = MFMA(w2a[ml][kf], ones, S);
        #pragma unroll
        for (int i = 0; i < 4; ++i)
            b2C[ml][i] = fmaf(-0.5f, S[i], SC * b2[(2 * w + ml) * 16 + 4 * quad + i]);
    }

    // L1 t-bias state (own 2 m-tiles) -- shared by both tiles (depends only on t)
    f4_t cin[2];
    unsigned w10p[4];
    {
        float t0 = ts[0];
        #pragma unroll
        for (int ml = 0; ml < 2; ++ml) {
            int f0 = (2 * w + ml) * 16 + 4 * quad;
            float wa = SC * W1[f0],     wb = SC * W1[f0 + 1];
            float wc = SC * W1[f0 + 2], wd = SC * W1[f0 + 3];
            w10p[2 * ml]     = ((unsigned)f2bf(wb) << 16) | f2bf(wa);
            w10p[2 * ml + 1] = ((unsigned)f2bf(wd) << 16) | f2bf(wc);
            cin[ml][0] = fmaf(t0, wa, SC * b1[f0]);
            cin[ml][1] = fmaf(t0, wb, SC * b1[f0 + 1]);
            cin[ml][2] = fmaf(t0, wc, SC * b1[f0 + 2]);
            cin[ml][3] = fmaf(t0, wd, SC * b1[f0 + 3]);
        }
    }

    // full-dim constants (x replicated)
    f4_t bmu[2];
    float vtr[2][4];
    #pragma unroll
    for (int mt = 0; mt < 2; ++mt)
        #pragma unroll
        for (int i = 0; i < 4; ++i) {
            int f = mt * 16 + 4 * quad + i;
            bmu[mt][i] = BETA * mu[f];
            vtr[mt][i] = vt[f];
        }

    // G fragments (hi/lo), both m-tiles, all waves (for full xg)
    bf8_t ghi[2], glo[2];
    #pragma unroll
    for (int mt = 0; mt < 2; ++mt) {
        #pragma unroll
        for (int j = 0; j < 8; ++j) {
            float gv = sG[(mt * 16 + m16) * DW + foS[j]];
            unsigned short hg = f2bf(gv);
            ghi[mt][j] = (short)hg;
            glo[mt][j] = (short)f2bf(gv - bf2f(hg));
        }
        agpr_pin(ghi[mt]); agpr_pin(glo[mt]);
    }

    // waves 0,1: L3 weights + b3C + dW state.  waves 2,3: a = GG^T frags.
    bf8_t w3a[4], ahi, alo;
    f4_t b3C, cwA, cwB;
    if (w < 2) {
        #pragma unroll
        for (int kf = 0; kf < 4; ++kf) {
            #pragma unroll
            for (int j = 0; j < 8; ++j)
                w3a[kf][j] = (short)f2bf(-2.f * W3[(ktG[kf] * 32 + foS[j]) * DW + w * 16 + m16]);
            agpr_pin(w3a[kf]);
        }
        f4_t S = {0, 0, 0, 0};
        #pragma unroll
        for (int kf = 0; kf < 4; ++kf) S = MFMA(w3a[kf], ones, S);
        #pragma unroll
        for (int i = 0; i < 4; ++i)
            b3C[i] = fmaf(-0.5f, S[i], b3[w * 16 + 4 * quad + i]);
        cwA = ((const f4_t*)(dWs + (size_t)browA * DW))[w * 4 + quad];
        cwB = ((const f4_t*)(dWs + (size_t)browB * DW))[w * 4 + quad];
    } else {
        int rowA = (w - 2) * 16 + m16;
        float gb[32];
        const f4_t* pb = (const f4_t*)(sG + rowA * DW);
        #pragma unroll
        for (int k4 = 0; k4 < 8; ++k4) {
            f4_t t = pb[k4];
            gb[4 * k4] = t[0]; gb[4 * k4 + 1] = t[1]; gb[4 * k4 + 2] = t[2]; gb[4 * k4 + 3] = t[3];
        }
        #pragma unroll
        for (int j = 0; j < 8; ++j) {
            const f4_t* pa = (const f4_t*)(sG + foS[j] * DW);
            float acc = 0.f;
            #pragma unroll
            for (int k4 = 0; k4 < 8; ++k4) {
                f4_t t = pa[k4];
                acc += t[0] * gb[4 * k4] + t[1] * gb[4 * k4 + 1]
                     + t[2] * gb[4 * k4 + 2] + t[3] * gb[4 * k4 + 3];
            }
            unsigned short h = f2bf(acc);
            ahi[j] = (short)h;
            alo[j] = (short)f2bf(acc - bf2f(h));
        }
        agpr_pin(ahi); agpr_pin(alo);
    }

    // ---- replicated x state for both tiles ----
    f4_t xrA[2], xrB[2];
    {
        const f4_t* pA = (const f4_t*)(x0 + (size_t)browA * DX);
        const f4_t* pB = (const f4_t*)(x0 + (size_t)browB * DX);
        xrA[0] = pA[quad]; xrA[1] = pA[4 + quad];
        xrB[0] = pB[quad]; xrB[1] = pB[4 + quad];
    }

    const float T = sts[NSTEPS];
    float tcur = sts[0];
    float llrA = 0.f, llrB = 0.f;

    float* xs_out = out;
    float* vs_out = out + (size_t)NSTEPS * BATCH * DX;
    float* ll_out = out + (size_t)2 * NSTEPS * BATCH * DX;

    #pragma unroll 1
    for (int s = 0; s < NSTEPS; ++s) {
        const float tnx    = sts[s + 1];
        const float dt     = tnx - tcur;
        const float sqdt   = __builtin_amdgcn_sqrtf(dt);
        const float invrem = rcp_hw(T - tcur + EPSG);

        f4_t nwA, nwB;
        if (w < 2) {
            int sn = (s + 1 < NSTEPS) ? s + 1 : s;
            const float* base = dWs + (size_t)sn * (BATCH * DW);
            nwA = ((const f4_t*)(base + (size_t)browA * DW))[w * 4 + quad];
            nwB = ((const f4_t*)(base + (size_t)browB * DW))[w * 4 + quad];
        }

        // ---- P1: L1 for both tiles; waves 2,3 also r + ra for both ----
        U8 xbA, xbB;
        xbA.u[0] = cvtpk(xrA[0][0], xrA[0][1]); xbA.u[1] = cvtpk(xrA[0][2], xrA[0][3]);
        xbA.u[2] = cvtpk(xrA[1][0], xrA[1][1]); xbA.u[3] = cvtpk(xrA[1][2], xrA[1][3]);
        xbB.u[0] = cvtpk(xrB[0][0], xrB[0][1]); xbB.u[1] = cvtpk(xrB[0][2], xrB[0][3]);
        xbB.u[2] = cvtpk(xrB[1][0], xrB[1][1]); xbB.u[3] = cvtpk(xrB[1][2], xrB[1][3]);
        U8 bhA, bhB;
        #pragma unroll
        for (int ml = 0; ml < 2; ++ml) {
            f4_t aA = MFMA(w1a[ml], xbA.v, cin[ml]);
            f4_t aB = MFMA(w1a[ml], xbB.v, cin[ml]);
            bhA.u[2 * ml]     = cvtpk(sigm_s(aA[0]), sigm_s(aA[1]));
            bhA.u[2 * ml + 1] = cvtpk(sigm_s(aA[2]), sigm_s(aA[3]));
            bhB.u[2 * ml]     = cvtpk(sigm_s(aB[0]), sigm_s(aB[1]));
            bhB.u[2 * ml + 1] = cvtpk(sigm_s(aB[2]), sigm_s(aB[3]));
        }
        *(uint4*)&sH1[0][w][lane][0] = make_uint4(bhA.u[0], bhA.u[1], bhA.u[2], bhA.u[3]);
        *(uint4*)&sH1[1][w][lane][0] = make_uint4(bhB.u[0], bhB.u[1], bhB.u[2], bhB.u[3]);

        float rrA[2][4], rrB[2][4];
        f4_t raA, raB;
        if (w >= 2) {
            #pragma unroll
            for (int mt = 0; mt < 2; ++mt)
                #pragma unroll
                for (int i = 0; i < 4; ++i) {
                    rrA[mt][i] = (vtr[mt][i] - xrA[mt][i]) * invrem;
                    rrB[mt][i] = (vtr[mt][i] - xrB[mt][i]) * invrem;
                }
            U8 rhA, rlA, rhB, rlB;
            hilo_pk(rrA[0][0], rrA[0][1], rhA.u[0], rlA.u[0]);
            hilo_pk(rrA[0][2], rrA[0][3], rhA.u[1], rlA.u[1]);
            hilo_pk(rrA[1][0], rrA[1][1], rhA.u[2], rlA.u[2]);
            hilo_pk(rrA[1][2], rrA[1][3], rhA.u[3], rlA.u[3]);
            hilo_pk(rrB[0][0], rrB[0][1], rhB.u[0], rlB.u[0]);
            hilo_pk(rrB[0][2], rrB[0][3], rhB.u[1], rlB.u[1]);
            hilo_pk(rrB[1][0], rrB[1][1], rhB.u[2], rlB.u[2]);
            hilo_pk(rrB[1][2], rrB[1][3], rhB.u[3], rlB.u[3]);
            raA = f4_t{0, 0, 0, 0};
            raA = MFMA(ahi, rhA.v, raA);
            raA = MFMA(ahi, rlA.v, raA);
            raA = MFMA(alo, rhA.v, raA);
            raB = f4_t{0, 0, 0, 0};
            raB = MFMA(ahi, rhB.v, raB);
            raB = MFMA(ahi, rlB.v, raB);
            raB = MFMA(alo, rhB.v, raB);
        }
        bar_lds();   // 1

        // ---- P2: L2 for both tiles (own-first K rotation) ----
        uint4 a1 = *(const uint4*)&sH1[0][ktG[1]][lane][0];
        uint4 a2 = *(const uint4*)&sH1[0][ktG[2]][lane][0];
        uint4 a3 = *(const uint4*)&sH1[0][ktG[3]][lane][0];
        uint4 c1 = *(const uint4*)&sH1[1][ktG[1]][lane][0];
        uint4 c2 = *(const uint4*)&sH1[1][ktG[2]][lane][0];
        uint4 c3 = *(const uint4*)&sH1[1][ktG[3]][lane][0];
        U8 fA1, fA2, fA3, fB1, fB2, fB3;
        fA1.u[0] = a1.x; fA1.u[1] = a1.y; fA1.u[2] = a1.z; fA1.u[3] = a1.w;
        fA2.u[0] = a2.x; fA2.u[1] = a2.y; fA2.u[2] = a2.z; fA2.u[3] = a2.w;
        fA3.u[0] = a3.x; fA3.u[1] = a3.y; fA3.u[2] = a3.z; fA3.u[3] = a3.w;
        fB1.u[0] = c1.x; fB1.u[1] = c1.y; fB1.u[2] = c1.z; fB1.u[3] = c1.w;
        fB2.u[0] = c2.x; fB2.u[1] = c2.y; fB2.u[2] = c2.z; fB2.u[3] = c2.w;
        fB3.u[0] = c3.x; fB3.u[1] = c3.y; fB3.u[2] = c3.z; fB3.u[3] = c3.w;
        U8 b2A, b2B;
        #pragma unroll
        for (int ml = 0; ml < 2; ++ml) {
            f4_t aA = b2C[ml];
            aA = MFMA(w2a[ml][0], bhA.v, aA);
            aA = MFMA(w2a[ml][1], fA1.v, aA);
            aA = MFMA(w2a[ml][2], fA2.v, aA);
            aA = MFMA(w2a[ml][3], fA3.v, aA);
            f4_t aB = b2C[ml];
            aB = MFMA(w2a[ml][0], bhB.v, aB);
            aB = MFMA(w2a[ml][1], fB1.v, aB);
            aB = MFMA(w2a[ml][2], fB2.v, aB);
            aB = MFMA(w2a[ml][3], fB3.v, aB);
            b2A.u[2 * ml]     = cvtpk(sigm_s(aA[0]), sigm_s(aA[1]));
            b2A.u[2 * ml + 1] = cvtpk(sigm_s(aA[2]), sigm_s(aA[3]));
            b2B.u[2 * ml]     = cvtpk(sigm_s(aB[0]), sigm_s(aB[1]));
            b2B.u[2 * ml + 1] = cvtpk(sigm_s(aB[2]), sigm_s(aB[3]));
        }
        *(uint4*)&sB2[0][w][lane][0] = make_uint4(b2A.u[0], b2A.u[1], b2A.u[2], b2A.u[3]);
        *(uint4*)&sB2[1][w][lane][0] = make_uint4(b2B.u[0], b2B.u[1], b2B.u[2], b2B.u[3]);
        bar_lds();   // 2

        // ---- P3: waves 0,1: L3 -> v, u-packs (both tiles).
        //          waves 2,3: ra writes + Gval (both tiles) ----
        f4_t vAA, vAB;
        if (w < 2) {
            uint4 p1 = *(const uint4*)&sB2[0][ktG[1]][lane][0];
            uint4 p2 = *(const uint4*)&sB2[0][ktG[2]][lane][0];
            uint4 p3 = *(const uint4*)&sB2[0][ktG[3]][lane][0];
            uint4 q1 = *(const uint4*)&sB2[1][ktG[1]][lane][0];
            uint4 q2 = *(const uint4*)&sB2[1][ktG[2]][lane][0];
            uint4 q3 = *(const uint4*)&sB2[1][ktG[3]][lane][0];
            U8 gA1, gA2, gA3, gB1, gB2, gB3;
            gA1.u[0] = p1.x; gA1.u[1] = p1.y; gA1.u[2] = p1.z; gA1.u[3] = p1.w;
            gA2.u[0] = p2.x; gA2.u[1] = p2.y; gA2.u[2] = p2.z; gA2.u[3] = p2.w;
            gA3.u[0] = p3.x; gA3.u[1] = p3.y; gA3.u[2] = p3.z; gA3.u[3] = p3.w;
            gB1.u[0] = q1.x; gB1.u[1] = q1.y; gB1.u[2] = q1.z; gB1.u[3] = q1.w;
            gB2.u[0] = q2.x; gB2.u[1] = q2.y; gB2.u[2] = q2.z; gB2.u[3] = q2.w;
            gB3.u[0] = q3.x; gB3.u[1] = q3.y; gB3.u[2] = q3.z; gB3.u[3] = q3.w;
            vAA = b3C;
            vAA = MFMA(w3a[0], b2A.v, vAA);
            vAA = MFMA(w3a[1], gA1.v, vAA);
            vAA = MFMA(w3a[2], gA2.v, vAA);
            vAA = MFMA(w3a[3], gA3.v, vAA);
            vAB = b3C;
            vAB = MFMA(w3a[0], b2B.v, vAB);
            vAB = MFMA(w3a[1], gB1.v, vAB);
            vAB = MFMA(w3a[2], gB2.v, vAB);
            vAB = MFMA(w3a[3], gB3.v, vAB);
            float uA0 = fmaf(vAA[0], dt, cwA[0] * sqdt);
            float uA1 = fmaf(vAA[1], dt, cwA[1] * sqdt);
            float uA2 = fmaf(vAA[2], dt, cwA[2] * sqdt);
            float uA3 = fmaf(vAA[3], dt, cwA[3] * sqdt);
            float uB0 = fmaf(vAB[0], dt, cwB[0] * sqdt);
            float uB1 = fmaf(vAB[1], dt, cwB[1] * sqdt);
            float uB2 = fmaf(vAB[2], dt, cwB[2] * sqdt);
            float uB3 = fmaf(vAB[3], dt, cwB[3] * sqdt);
            unsigned h0, h1, l0, l1;
            hilo_pk(uA0, uA1, h0, l0);
            hilo_pk(uA2, uA3, h1, l1);
            *(uint2*)&sUH[0][w][lane][0] = make_uint2(h0, h1);
            *(uint2*)&sUL[0][w][lane][0] = make_uint2(l0, l1);
            hilo_pk(uB0, uB1, h0, l0);
            hilo_pk(uB2, uB3, h1, l1);
            *(uint2*)&sUH[1][w][lane][0] = make_uint2(h0, h1);
            *(uint2*)&sUL[1][w][lane][0] = make_uint2(l0, l1);
        } else {
            sRA[0][w - 2][lane] = raA;
            sRA[1][w - 2][lane] = raB;
            int tw = w - 2;
            float gsA = 0.f, gsB = 0.f;
            #pragma unroll
            for (int i = 0; i < 4; ++i) {
                float fbA = fmaf(-BETA, xrA[tw][i], bmu[tw][i]);
                float fbB = fmaf(-BETA, xrB[tw][i], bmu[tw][i]);
                gsA = fmaf(fbA, rrA[tw][i], gsA);
                gsA = fmaf(-0.5f * rrA[tw][i], raA[i], gsA);
                gsB = fmaf(fbB, rrB[tw][i], gsB);
                gsB = fmaf(-0.5f * rrB[tw][i], raB[i], gsB);
            }
            llrA = fmaf(gsA, dt, llrA);
            llrB = fmaf(gsB, dt, llrB);
        }
        bar_lds();   // 3

        // ---- P4: all waves: full xg + full x-update for both tiles ----
        uint2 uaA = *(const uint2*)&sUH[0][0][lane][0];
        uint2 ubA = *(const uint2*)&sUH[0][1][lane][0];
        uint2 laA = *(const uint2*)&sUL[0][0][lane][0];
        uint2 lbA = *(const uint2*)&sUL[0][1][lane][0];
        uint2 uaB = *(const uint2*)&sUH[1][0][lane][0];
        uint2 ubB = *(const uint2*)&sUH[1][1][lane][0];
        uint2 laB = *(const uint2*)&sUL[1][0][lane][0];
        uint2 lbB = *(const uint2*)&sUL[1][1][lane][0];
        U8 uhA, ulA, uhB, ulB;
        uhA.u[0] = uaA.x; uhA.u[1] = uaA.y; uhA.u[2] = ubA.x; uhA.u[3] = ubA.y;
        ulA.u[0] = laA.x; ulA.u[1] = laA.y; ulA.u[2] = lbA.x; ulA.u[3] = lbA.y;
        uhB.u[0] = uaB.x; uhB.u[1] = uaB.y; uhB.u[2] = ubB.x; uhB.u[3] = ubB.y;
        ulB.u[0] = laB.x; ulB.u[1] = laB.y; ulB.u[2] = lbB.x; ulB.u[3] = lbB.y;
        f4_t rA0 = sRA[0][0][lane];
        f4_t rA1 = sRA[0][1][lane];
        f4_t rB0 = sRA[1][0][lane];
        f4_t rB1 = sRA[1][1][lane];
        f4_t xgA0 = {0, 0, 0, 0}, xgA1 = {0, 0, 0, 0};
        f4_t xgB0 = {0, 0, 0, 0}, xgB1 = {0, 0, 0, 0};
        xgA0 = MFMA(ghi[0], uhA.v, xgA0);
        xgA0 = MFMA(ghi[0], ulA.v, xgA0);
        xgA0 = MFMA(glo[0], uhA.v, xgA0);
        xgA1 = MFMA(ghi[1], uhA.v, xgA1);
        xgA1 = MFMA(ghi[1], ulA.v, xgA1);
        xgA1 = MFMA(glo[1], uhA.v, xgA1);
        xgB0 = MFMA(ghi[0], uhB.v, xgB0);
        xgB0 = MFMA(ghi[0], ulB.v, xgB0);
        xgB0 = MFMA(glo[0], uhB.v, xgB0);
        xgB1 = MFMA(ghi[1], uhB.v, xgB1);
        xgB1 = MFMA(ghi[1], ulB.v, xgB1);
        xgB1 = MFMA(glo[1], uhB.v, xgB1);
        f4_t xoA0, xoA1, xoB0, xoB1;
        #pragma unroll
        for (int i = 0; i < 4; ++i) {
            float fbA0 = fmaf(-BETA, xrA[0][i], bmu[0][i]);
            float fbA1 = fmaf(-BETA, xrA[1][i], bmu[1][i]);
            float fbB0 = fmaf(-BETA, xrB[0][i], bmu[0][i]);
            float fbB1 = fmaf(-BETA, xrB[1][i], bmu[1][i]);
            xoA0[i] = fmaf(fbA0 + rA0[i], dt, xrA[0][i]) + xgA0[i];
            xoA1[i] = fmaf(fbA1 + rA1[i], dt, xrA[1][i]) + xgA1[i];
            xoB0[i] = fmaf(fbB0 + rB0[i], dt, xrB[0][i]) + xgB0[i];
            xoB1[i] = fmaf(fbB1 + rB1[i], dt, xrB[1][i]) + xgB1[i];
        }
        xrA[0] = xoA0; xrA[1] = xoA1;
        xrB[0] = xoB0; xrB[1] = xoB1;
        if (w < 2) {
            f4_t* pxA = (f4_t*)(xs_out + (size_t)s * (BATCH * DX) + (size_t)browA * DX);
            f4_t* pxB = (f4_t*)(xs_out + (size_t)s * (BATCH * DX) + (size_t)browB * DX);
            f4_t* pvA = (f4_t*)(vs_out + (size_t)s * (BATCH * DX) + (size_t)browA * DX);
            f4_t* pvB = (f4_t*)(vs_out + (size_t)s * (BATCH * DX) + (size_t)browB * DX);
            pxA[w * 4 + quad] = (w == 0) ? xoA0 : xoA1;
            pxB[w * 4 + quad] = (w == 0) ? xoB0 : xoB1;
            pvA[w * 4 + quad] = vAA;
            pvB[w * 4 + quad] = vAB;
            cwA = nwA; cwB = nwB;
        }

        // roll cin (shared) + time
        #pragma unroll
        for (int ml = 0; ml < 2; ++ml) {
            unsigned wa = w10p[2 * ml], wb = w10p[2 * ml + 1];
            cin[ml][0] = fmaf(dt, unplo(wa), cin[ml][0]);
            cin[ml][1] = fmaf(dt, unphi(wa), cin[ml][1]);
            cin[ml][2] = fmaf(dt, unplo(wb), cin[ml][2]);
            cin[ml][3] = fmaf(dt, unphi(wb), cin[ml][3]);
        }
        tcur = tnx;
    }

    // ---- ll: waves 2,3 hold tile partials; reduce + combine ----
    if (w >= 2) {
        llrA += __shfl_xor(llrA, 16, 64);
        llrA += __shfl_xor(llrA, 32, 64);
        llrB += __shfl_xor(llrB, 16, 64);
        llrB += __shfl_xor(llrB, 32, 64);
        if (lane < 16) {
            sLL[0][w - 2][lane] = llrA;
            sLL[1][w - 2][lane] = llrB;
        }
    }
    bar_lds();
    if (w == 0 && lane < 16) {
        ll_out[r0 + lane]      = sLL[0][0][lane] + sLL[0][1][lane];
        ll_out[r0 + 16 + lane] = sLL[1][0][lane] + sLL[1][1][lane];
    }
}

extern "C" void kernel_launch(void* const* d_in, const int* in_sizes, int n_in,
                              void* d_out, int out_size, void* d_ws, size_t ws_size,
                              hipStream_t stream) {
    const float* x0 = (const float*)d_in[0];
    const float* ts = (const float*)d_in[1];
    const float* dWs = (const float*)d_in[2];
    const float* W1 = (const float*)d_in[3];
    const float* b1 = (const float*)d_in[4];
    const float* W2 = (const float*)d_in[5];
    const float* b2 = (const float*)d_in[6];
    const float* W3 = (const float*)d_in[7];
    const float* b3 = (const float*)d_in[8];
    const float* G  = (const float*)d_in[9];
    const float* mu = (const float*)d_in[10];
    const float* vt = (const float*)d_in[11];
    hipLaunchKernelGGL(sde_kernel, dim3(BATCH / 32), dim3(256), 0, stream,
                       x0, ts, dWs, W1, b1, W2, b2, W3, b3, G, mu, vt, (float*)d_out);
}

// Round 8
// 726.678 us; speedup vs baseline: 1.4537x; 1.4537x over previous
//
#include <hip/hip_runtime.h>
#include <math.h>

#define NSTEPS 500
#define BATCH  1024
#define DX     32
#define DW     32
#define HDIM   128
#define BETA   0.5f
#define EPSG   1e-4f
#define SC     2.8853900817779268f   // 2*log2(e): pre-scale for exp2-based sigmoid

typedef short bf8_t __attribute__((ext_vector_type(8)));
typedef float f4_t  __attribute__((ext_vector_type(4)));

union U8 { bf8_t v; unsigned u[4]; };

__device__ __forceinline__ f4_t MFMA(bf8_t a, bf8_t b, f4_t c) {
    return __builtin_amdgcn_mfma_f32_16x16x32_bf16(a, b, c, 0, 0, 0);
}

__device__ __forceinline__ unsigned short f2bf(float x) {   // RNE f32->bf16
    unsigned u = __float_as_uint(x);
    u += 0x7fffu + ((u >> 16) & 1u);
    return (unsigned short)(u >> 16);
}
__device__ __forceinline__ float bf2f(unsigned short h) {
    return __uint_as_float(((unsigned)h) << 16);
}
__device__ __forceinline__ unsigned cvtpk(float a, float b) {
    unsigned r;
    asm("v_cvt_pk_bf16_f32 %0, %1, %2" : "=v"(r) : "v"(a), "v"(b));
    return r;
}
__device__ __forceinline__ float unplo(unsigned u) { return __uint_as_float(u << 16); }
__device__ __forceinline__ float unphi(unsigned u) { return __uint_as_float(u & 0xffff0000u); }

__device__ __forceinline__ float exp2_hw(float x) {
    float r; asm("v_exp_f32 %0, %1" : "=v"(r) : "v"(x)); return r;
}
__device__ __forceinline__ float rcp_hw(float x) {
    float r; asm("v_rcp_f32 %0, %1" : "=v"(r) : "v"(x)); return r;
}
// sg = 1/(2^zs + 1); tanh(z) = 1 - 2*sg folded into next layer's weights/bias
__device__ __forceinline__ float sigm_s(float zs) {
    return rcp_hw(exp2_hw(zs) + 1.f);
}
__device__ __forceinline__ void hilo_pk(float a, float b, unsigned& hp, unsigned& lp) {
    hp = cvtpk(a, b);
    lp = cvtpk(a - unplo(hp), b - unphi(hp));
}
__device__ __forceinline__ void agpr_pin(bf8_t& v) { asm("" : "+a"(v)); }

// LDS barrier: orders LDS (lgkmcnt) but lets global loads/stores float across.
// SINGLE s_barrier (r7 accidentally had two).
__device__ __forceinline__ void bar_lds() {
    __builtin_amdgcn_sched_barrier(0);
    asm volatile("s_waitcnt lgkmcnt(0)" ::: "memory");
    __builtin_amdgcn_s_barrier();
    __builtin_amdgcn_sched_barrier(0);
}

// ============================================================================
// Round 8: UNIFORM 2-barrier design.  All 4 waves do IDENTICAL work except the
// L1/L2 feature split (own 2 m-tiles) and the output-store assignment:
//   P1: r + hi/lo packs + ra (full, 6 MFMA) + L1 own + h1 write
//   bar1
//   P2: read partner h1 (3) | Gval filler | L2 own + b2 write
//   bar2
//   P3: read partner b2 (3) | dW*sqdt + cin filler | L3 full (8 MFMA, redundant)
//       + u + packs + xg (6 MFMA) + x-update (all replicated, bitwise identical)
// No sRA/sUH/sUL exchanges, no bar3, zero arrival spread (uniform waves).
// Single-buffered sH1/sB2 is race-free: each buffer's read(s) and write(s+1)
// are separated by one lgkm-draining barrier.  ktG rotation keeps fragment
// assembly statically indexed.  Weights in AGPRs.
// ============================================================================
__global__ __launch_bounds__(256, 1)
void sde_kernel(const float* __restrict__ x0, const float* __restrict__ ts,
                const float* __restrict__ dWs,
                const float* __restrict__ W1, const float* __restrict__ b1,
                const float* __restrict__ W2, const float* __restrict__ b2,
                const float* __restrict__ W3, const float* __restrict__ b3,
                const float* __restrict__ G,  const float* __restrict__ mu,
                const float* __restrict__ vt, float* __restrict__ out)
{
    __shared__ float sts[NSTEPS + 1];
    __shared__ __align__(16) float sG[DX * DW];
    __shared__ __align__(16) unsigned sH1[4][64][4];
    __shared__ __align__(16) unsigned sB2[4][64][4];

    const int tid  = threadIdx.x;
    const int w    = tid >> 6;       // wave id 0..3
    const int lane = tid & 63;
    const int m16  = lane & 15;      // batch column
    const int quad = lane >> 4;
    const int r0   = blockIdx.x * 16;
    const int brow = r0 + m16;

    for (int i = tid; i <= NSTEPS; i += 256) sts[i] = ts[i];
    for (int i = tid; i < DX * DW; i += 256) sG[i] = G[i];
    __syncthreads();

    // sigma k-slot map (group-local, 32-wide) and k-tile rotation (own-first)
    int foS[8], ktG[4];
    #pragma unroll
    for (int j = 0; j < 8; ++j) foS[j] = (j < 4) ? (4 * quad + j) : (16 + 4 * quad + (j - 4));
    #pragma unroll
    for (int kf = 0; kf < 4; ++kf) ktG[kf] = (w + kf) & 3;

    // ---- L1/L2 weight fragments (own 2 m-tiles) ----
    bf8_t w1a[2];
    #pragma unroll
    for (int ml = 0; ml < 2; ++ml) {
        int mtg = 2 * w + ml;
        #pragma unroll
        for (int j = 0; j < 8; ++j)
            w1a[ml][j] = (short)f2bf(SC * W1[(1 + foS[j]) * HDIM + mtg * 16 + m16]);
        agpr_pin(w1a[ml]);
    }
    bf8_t w2a[2][4];
    #pragma unroll
    for (int ml = 0; ml < 2; ++ml) {
        int mtg = 2 * w + ml;
        #pragma unroll
        for (int kf = 0; kf < 4; ++kf) {
            #pragma unroll
            for (int j = 0; j < 8; ++j)
                w2a[ml][kf][j] = (short)f2bf(-2.f * SC * W2[(ktG[kf] * 32 + foS[j]) * HDIM + mtg * 16 + m16]);
            agpr_pin(w2a[ml][kf]);
        }
    }
    // ---- L3 weights: FULL (both v m-tiles) on every wave, rotated K order ----
    bf8_t w3a[2][4];
    #pragma unroll
    for (int mt = 0; mt < 2; ++mt)
        #pragma unroll
        for (int kf = 0; kf < 4; ++kf) {
            #pragma unroll
            for (int j = 0; j < 8; ++j)
                w3a[mt][kf][j] = (short)f2bf(-2.f * W3[(ktG[kf] * 32 + foS[j]) * DW + mt * 16 + m16]);
            agpr_pin(w3a[mt][kf]);
        }

    bf8_t ones;
    #pragma unroll
    for (int j = 0; j < 8; ++j) ones[j] = (short)0x3f80;

    // folded C-inits
    f4_t b2C[2];
    #pragma unroll
    for (int ml = 0; ml < 2; ++ml) {
        f4_t S = {0, 0, 0, 0};
        #pragma unroll
        for (int kf = 0; kf < 4; ++kf) S = MFMA(w2a[ml][kf], ones, S);
        #pragma unroll
        for (int i = 0; i < 4; ++i)
            b2C[ml][i] = fmaf(-0.5f, S[i], SC * b2[(2 * w + ml) * 16 + 4 * quad + i]);
    }
    f4_t b3C[2];
    #pragma unroll
    for (int mt = 0; mt < 2; ++mt) {
        f4_t S = {0, 0, 0, 0};
        #pragma unroll
        for (int kf = 0; kf < 4; ++kf) S = MFMA(w3a[mt][kf], ones, S);
        #pragma unroll
        for (int i = 0; i < 4; ++i)
            b3C[mt][i] = fmaf(-0.5f, S[i], b3[mt * 16 + 4 * quad + i]);
    }

    // L1 t-bias state (own 2 m-tiles)
    f4_t cin[2];
    unsigned w10p[4];
    {
        float t0 = ts[0];
        #pragma unroll
        for (int ml = 0; ml < 2; ++ml) {
            int f0 = (2 * w + ml) * 16 + 4 * quad;
            float wa = SC * W1[f0],     wb = SC * W1[f0 + 1];
            float wc = SC * W1[f0 + 2], wd = SC * W1[f0 + 3];
            w10p[2 * ml]     = ((unsigned)f2bf(wb) << 16) | f2bf(wa);
            w10p[2 * ml + 1] = ((unsigned)f2bf(wd) << 16) | f2bf(wc);
            cin[ml][0] = fmaf(t0, wa, SC * b1[f0]);
            cin[ml][1] = fmaf(t0, wb, SC * b1[f0 + 1]);
            cin[ml][2] = fmaf(t0, wc, SC * b1[f0 + 2]);
            cin[ml][3] = fmaf(t0, wd, SC * b1[f0 + 3]);
        }
    }

    // full-dim constants
    f4_t bmu[2];
    float vtr[2][4];
    #pragma unroll
    for (int mt = 0; mt < 2; ++mt)
        #pragma unroll
        for (int i = 0; i < 4; ++i) {
            int f = mt * 16 + 4 * quad + i;
            bmu[mt][i] = BETA * mu[f];
            vtr[mt][i] = vt[f];
        }

    // G and a = G G^T fragments (hi/lo), BOTH m-tiles, every wave
    bf8_t ghi[2], glo[2], ahi[2], alo[2];
    #pragma unroll
    for (int mt = 0; mt < 2; ++mt) {
        int rowA = mt * 16 + m16;
        float gb[32];
        const f4_t* pb = (const f4_t*)(sG + rowA * DW);
        #pragma unroll
        for (int k4 = 0; k4 < 8; ++k4) {
            f4_t t = pb[k4];
            gb[4 * k4] = t[0]; gb[4 * k4 + 1] = t[1]; gb[4 * k4 + 2] = t[2]; gb[4 * k4 + 3] = t[3];
        }
        #pragma unroll
        for (int j = 0; j < 8; ++j) {
            const f4_t* pa = (const f4_t*)(sG + foS[j] * DW);
            float acc = 0.f;
            #pragma unroll
            for (int k4 = 0; k4 < 8; ++k4) {
                f4_t t = pa[k4];
                acc += t[0] * gb[4 * k4] + t[1] * gb[4 * k4 + 1]
                     + t[2] * gb[4 * k4 + 2] + t[3] * gb[4 * k4 + 3];
            }
            unsigned short h = f2bf(acc);
            ahi[mt][j] = (short)h;
            alo[mt][j] = (short)f2bf(acc - bf2f(h));
            float gv = sG[rowA * DW + foS[j]];
            unsigned short hg = f2bf(gv);
            ghi[mt][j] = (short)hg;
            glo[mt][j] = (short)f2bf(gv - bf2f(hg));
        }
        agpr_pin(ghi[mt]); agpr_pin(glo[mt]);
        agpr_pin(ahi[mt]); agpr_pin(alo[mt]);
    }

    // ---- replicated state: x (full 32 dims), dW (full) ----
    f4_t xr[2];
    {
        const f4_t* p = (const f4_t*)(x0 + (size_t)brow * DX);
        xr[0] = p[quad]; xr[1] = p[4 + quad];
    }
    f4_t cw0, cw1;
    {
        const f4_t* p = (const f4_t*)(dWs + (size_t)brow * DW);
        cw0 = p[quad]; cw1 = p[4 + quad];
    }

    const float T = sts[NSTEPS];
    float tcur = sts[0];
    float llr = 0.f;

    float* xs_out = out;
    float* vs_out = out + (size_t)NSTEPS * BATCH * DX;
    float* ll_out = out + (size_t)2 * NSTEPS * BATCH * DX;

    const int g1 = (w + 1) & 3, g2 = (w + 2) & 3, g3 = (w + 3) & 3;

    #pragma unroll 1
    for (int s = 0; s < NSTEPS; ++s) {
        const float tnx    = sts[s + 1];
        const float dt     = tnx - tcur;
        const float sqdt   = __builtin_amdgcn_sqrtf(dt);
        const float invrem = rcp_hw(T - tcur + EPSG);

        // prefetch next dW (floats across the whole step)
        f4_t nw0, nw1;
        {
            int sn = (s + 1 < NSTEPS) ? s + 1 : s;
            const f4_t* p = (const f4_t*)(dWs + (size_t)sn * (BATCH * DW) + (size_t)brow * DW);
            nw0 = p[quad]; nw1 = p[4 + quad];
        }

        // ---- P1: r + fb + packs + ra (full, all waves); L1 own; h1 write ----
        float rr[2][4], fb[2][4];
        #pragma unroll
        for (int mt = 0; mt < 2; ++mt)
            #pragma unroll
            for (int i = 0; i < 4; ++i) {
                rr[mt][i] = (vtr[mt][i] - xr[mt][i]) * invrem;
                fb[mt][i] = fmaf(-BETA, xr[mt][i], bmu[mt][i]);
            }
        U8 rh, rl;
        hilo_pk(rr[0][0], rr[0][1], rh.u[0], rl.u[0]);
        hilo_pk(rr[0][2], rr[0][3], rh.u[1], rl.u[1]);
        hilo_pk(rr[1][0], rr[1][1], rh.u[2], rl.u[2]);
        hilo_pk(rr[1][2], rr[1][3], rh.u[3], rl.u[3]);
        f4_t ra0 = {0, 0, 0, 0}, ra1 = {0, 0, 0, 0};
        ra0 = MFMA(ahi[0], rh.v, ra0);
        ra0 = MFMA(ahi[0], rl.v, ra0);
        ra0 = MFMA(alo[0], rh.v, ra0);
        ra1 = MFMA(ahi[1], rh.v, ra1);
        ra1 = MFMA(ahi[1], rl.v, ra1);
        ra1 = MFMA(alo[1], rh.v, ra1);

        U8 xb;
        xb.u[0] = cvtpk(xr[0][0], xr[0][1]); xb.u[1] = cvtpk(xr[0][2], xr[0][3]);
        xb.u[2] = cvtpk(xr[1][0], xr[1][1]); xb.u[3] = cvtpk(xr[1][2], xr[1][3]);
        U8 bhO;
        #pragma unroll
        for (int ml = 0; ml < 2; ++ml) {
            f4_t acc = MFMA(w1a[ml], xb.v, cin[ml]);
            bhO.u[2 * ml]     = cvtpk(sigm_s(acc[0]), sigm_s(acc[1]));
            bhO.u[2 * ml + 1] = cvtpk(sigm_s(acc[2]), sigm_s(acc[3]));
        }
        *(uint4*)&sH1[w][lane][0] = make_uint4(bhO.u[0], bhO.u[1], bhO.u[2], bhO.u[3]);
        bar_lds();   // 1

        // ---- P2: partner h1 reads first; Gval as latency filler; L2 own ----
        uint4 t1 = *(const uint4*)&sH1[g1][lane][0];
        uint4 t2 = *(const uint4*)&sH1[g2][lane][0];
        uint4 t3 = *(const uint4*)&sH1[g3][lane][0];
        {   // filler: Gval partial (uses P1 registers only)
            float gs = 0.f;
            #pragma unroll
            for (int i = 0; i < 4; ++i) {
                gs = fmaf(fb[0][i], rr[0][i], gs);
                gs = fmaf(-0.5f * rr[0][i], ra0[i], gs);
                gs = fmaf(fb[1][i], rr[1][i], gs);
                gs = fmaf(-0.5f * rr[1][i], ra1[i], gs);
            }
            llr = fmaf(gs, dt, llr);
        }
        U8 f1, f2, f3;
        f1.u[0] = t1.x; f1.u[1] = t1.y; f1.u[2] = t1.z; f1.u[3] = t1.w;
        f2.u[0] = t2.x; f2.u[1] = t2.y; f2.u[2] = t2.z; f2.u[3] = t2.w;
        f3.u[0] = t3.x; f3.u[1] = t3.y; f3.u[2] = t3.z; f3.u[3] = t3.w;
        U8 b2O;
        #pragma unroll
        for (int ml = 0; ml < 2; ++ml) {
            f4_t acc = b2C[ml];
            acc = MFMA(w2a[ml][0], bhO.v, acc);
            acc = MFMA(w2a[ml][1], f1.v, acc);
            acc = MFMA(w2a[ml][2], f2.v, acc);
            acc = MFMA(w2a[ml][3], f3.v, acc);
            b2O.u[2 * ml]     = cvtpk(sigm_s(acc[0]), sigm_s(acc[1]));
            b2O.u[2 * ml + 1] = cvtpk(sigm_s(acc[2]), sigm_s(acc[3]));
        }
        *(uint4*)&sB2[w][lane][0] = make_uint4(b2O.u[0], b2O.u[1], b2O.u[2], b2O.u[3]);
        bar_lds();   // 2

        // ---- P3: partner b2 reads; dW/cin filler; full L3 + u + xg + update ----
        uint4 p1 = *(const uint4*)&sB2[g1][lane][0];
        uint4 p2 = *(const uint4*)&sB2[g2][lane][0];
        uint4 p3 = *(const uint4*)&sB2[g3][lane][0];
        f4_t dws0, dws1;
        #pragma unroll
        for (int i = 0; i < 4; ++i) { dws0[i] = cw0[i] * sqdt; dws1[i] = cw1[i] * sqdt; }
        #pragma unroll
        for (int ml = 0; ml < 2; ++ml) {   // filler: cin roll
            unsigned wa = w10p[2 * ml], wb = w10p[2 * ml + 1];
            cin[ml][0] = fmaf(dt, unplo(wa), cin[ml][0]);
            cin[ml][1] = fmaf(dt, unphi(wa), cin[ml][1]);
            cin[ml][2] = fmaf(dt, unplo(wb), cin[ml][2]);
            cin[ml][3] = fmaf(dt, unphi(wb), cin[ml][3]);
        }
        U8 q1, q2, q3;
        q1.u[0] = p1.x; q1.u[1] = p1.y; q1.u[2] = p1.z; q1.u[3] = p1.w;
        q2.u[0] = p2.x; q2.u[1] = p2.y; q2.u[2] = p2.z; q2.u[3] = p2.w;
        q3.u[0] = p3.x; q3.u[1] = p3.y; q3.u[2] = p3.z; q3.u[3] = p3.w;
        f4_t v0a = b3C[0], v1a = b3C[1];
        v0a = MFMA(w3a[0][0], b2O.v, v0a);
        v1a = MFMA(w3a[1][0], b2O.v, v1a);
        v0a = MFMA(w3a[0][1], q1.v, v0a);
        v1a = MFMA(w3a[1][1], q1.v, v1a);
        v0a = MFMA(w3a[0][2], q2.v, v0a);
        v1a = MFMA(w3a[1][2], q2.v, v1a);
        v0a = MFMA(w3a[0][3], q3.v, v0a);
        v1a = MFMA(w3a[1][3], q3.v, v1a);

        float u_[2][4];
        #pragma unroll
        for (int i = 0; i < 4; ++i) {
            u_[0][i] = fmaf(v0a[i], dt, dws0[i]);
            u_[1][i] = fmaf(v1a[i], dt, dws1[i]);
        }
        U8 uh, ul;
        hilo_pk(u_[0][0], u_[0][1], uh.u[0], ul.u[0]);
        hilo_pk(u_[0][2], u_[0][3], uh.u[1], ul.u[1]);
        hilo_pk(u_[1][0], u_[1][1], uh.u[2], ul.u[2]);
        hilo_pk(u_[1][2], u_[1][3], uh.u[3], ul.u[3]);
        f4_t xg0 = {0, 0, 0, 0}, xg1 = {0, 0, 0, 0};
        xg0 = MFMA(ghi[0], uh.v, xg0);
        xg1 = MFMA(ghi[1], uh.v, xg1);
        xg0 = MFMA(ghi[0], ul.v, xg0);
        xg1 = MFMA(ghi[1], ul.v, xg1);
        xg0 = MFMA(glo[0], uh.v, xg0);
        xg1 = MFMA(glo[1], uh.v, xg1);

        f4_t xo0, xo1;
        #pragma unroll
        for (int i = 0; i < 4; ++i) {
            xo0[i] = fmaf(fb[0][i] + ra0[i], dt, xr[0][i]) + xg0[i];
            xo1[i] = fmaf(fb[1][i] + ra1[i], dt, xr[1][i]) + xg1[i];
        }
        xr[0] = xo0; xr[1] = xo1;

        // one store per wave (values identical across waves)
        {
            float* xbase = xs_out + (size_t)s * (BATCH * DX) + (size_t)brow * DX;
            float* vbase = vs_out + (size_t)s * (BATCH * DX) + (size_t)brow * DX;
            if (w == 0)      ((f4_t*)xbase)[quad]     = xo0;
            else if (w == 1) ((f4_t*)xbase)[4 + quad] = xo1;
            else if (w == 2) ((f4_t*)vbase)[quad]     = v0a;
            else             ((f4_t*)vbase)[4 + quad] = v1a;
        }

        cw0 = nw0; cw1 = nw1;
        tcur = tnx;
    }

    // ll: identical on all waves; wave 0 reduces quads and stores
    if (w == 0) {
        llr += __shfl_xor(llr, 16, 64);
        llr += __shfl_xor(llr, 32, 64);
        if (lane < 16) ll_out[r0 + lane] = llr;
    }
}

extern "C" void kernel_launch(void* const* d_in, const int* in_sizes, int n_in,
                              void* d_out, int out_size, void* d_ws, size_t ws_size,
                              hipStream_t stream) {
    const float* x0 = (const float*)d_in[0];
    const float* ts = (const float*)d_in[1];
    const float* dWs = (const float*)d_in[2];
    const float* W1 = (const float*)d_in[3];
    const float* b1 = (const float*)d_in[4];
    const float* W2 = (const float*)d_in[5];
    const float* b2 = (const float*)d_in[6];
    const float* W3 = (const float*)d_in[7];
    const float* b3 = (const float*)d_in[8];
    const float* G  = (const float*)d_in[9];
    const float* mu = (const float*)d_in[10];
    const float* vt = (const float*)d_in[11];
    hipLaunchKernelGGL(sde_kernel, dim3(BATCH / 16), dim3(256), 0, stream,
                       x0, ts, dWs, W1, b1, W2, b2, W3, b3, G, mu, vt, (float*)d_out);
}